// Round 8
// baseline (530.947 us; speedup 1.0000x reference)
//
#include <hip/hip_runtime.h>
#include <hip/hip_cooperative_groups.h>

namespace cg = cooperative_groups;

#define T_STEPS 256
#define BATCH   128
#define DIM     1024
#define NROWS   (T_STEPS * BATCH)        // 32768
#define TOTROWS (NROWS + 2 * BATCH)      // 33024

typedef float vfloat4 __attribute__((ext_vector_type(4)));

// ws float-offset layout
#define WS_M     0                        // float[4096]
#define WS_V     4096                     // float[4]
#define WS_CB    4128                     // float[4]
#define WS_QX    8192                     // float4[32768]
#define WS_HSEQ  (WS_QX + 4 * NROWS)      // float[32768]   = 139264
#define WS_CFIN  (WS_HSEQ + NROWS)        // float[128]     = 172032
#define WS_MPART (WS_CFIN + 128)          // float[64*4096] = 172160
#define WS_VPART (WS_MPART + 64 * 4096)   // float[64*4]    = 434304
#define WS_CPART (WS_VPART + 256)         // float[64*4]    = 434560

__device__ __forceinline__ float fast_tanh(float x) {
    float e = __expf(2.f * x);
    return (e - 1.f) * __builtin_amdgcn_rcpf(e + 1.f);
}

__device__ __forceinline__ void rec_step(float4 q,
                                         float b0, float b1, float b2, float b3,
                                         float v0, float v1, float v2, float v3,
                                         float& h, float& c) {
    float z0 = __cosf(q.x + b0 + h * v0);
    float z1 = __cosf(q.y + b1 + h * v1);
    float z2 = __cosf(q.z + b2 + h * v2);
    float z3 = __cosf(q.w + b3 + h * v3);
    float e1 = z0 * z1;
    float e2 = e1 * z2;
    float e3 = e2 * z3;
    float e0 = z1 * z2 * z3;
    float x0 = __expf(e0), x1 = __expf(e1), x2 = __expf(e2), x3 = __expf(e3);
    float inv = __builtin_amdgcn_rcpf(x0 + x1 + x2 + x3);
    float f  = x0 * inv;
    float i_ = x1 * inv;
    float g  = x2 * inv;
    float o  = x3 * inv;
    c = f * c + i_ * fast_tanh(g);
    h = o * fast_tanh(c);
}

__global__ __launch_bounds__(256, 1) void k_all(
        const float* __restrict__ x,   const float* __restrict__ Wi,
        const float* __restrict__ Wh,  const float* __restrict__ bi,
        const float* __restrict__ bh,  const float* __restrict__ Wq,
        const float* __restrict__ bq,  const float* __restrict__ theta,
        float* __restrict__ out,
        float* __restrict__ M,     float* __restrict__ v,
        float* __restrict__ cb,    float4* __restrict__ qx4,
        float* __restrict__ hseq,  float* __restrict__ cfin,
        float* __restrict__ Mpart, float* __restrict__ vpart,
        float* __restrict__ cpart) {
    cg::grid_group grid = cg::this_grid();
    int blk  = blockIdx.x;
    int tid  = threadIdx.x;
    int wave = tid >> 6;
    int lane = tid & 63;
    int NB   = gridDim.x;

    // ---------- Phase A: partials (direct stores, no atomics/memset) ----------
    if (blk < 64) {
        // Mpart[blk] = partial of Wq@Wi over j in [blk*16, blk*16+16)
        int j0 = blk * 16;
        float* base = Mpart + (size_t)blk * 4096;
        #pragma unroll
        for (int db = 0; db < 4; db++) {
            int d = db * 256 + tid;
            float a0 = 0.f, a1 = 0.f, a2 = 0.f, a3 = 0.f;
            #pragma unroll 4
            for (int jj = 0; jj < 16; jj++) {
                int j = j0 + jj;
                float wv = Wi[(size_t)j * DIM + d];   // coalesced 1KB/instr
                a0 += Wq[0 * DIM + j] * wv;           // uniform -> scalar loads
                a1 += Wq[1 * DIM + j] * wv;
                a2 += Wq[2 * DIM + j] * wv;
                a3 += Wq[3 * DIM + j] * wv;
            }
            base[0 * DIM + d] = a0;
            base[1 * DIM + d] = a1;
            base[2 * DIM + d] = a2;
            base[3 * DIM + d] = a3;
        }
    } else if (blk < 128) {
        // Wh rowsum partials -> vpart/cpart; each wave handles 4 rows
        int bb_ = blk - 64;
        int j0  = bb_ * 16 + wave * 4;
        float sv0 = 0.f, sv1 = 0.f, sv2 = 0.f, sv3 = 0.f;
        float sc0 = 0.f, sc1 = 0.f, sc2 = 0.f, sc3 = 0.f;
        #pragma unroll
        for (int jj = 0; jj < 4; jj++) {
            int j = j0 + jj;
            const float4* row = (const float4*)(Wh + (size_t)j * DIM);
            float s = 0.f;
            #pragma unroll
            for (int k = 0; k < 4; k++) {
                float4 t4 = row[k * 64 + lane];
                s += t4.x + t4.y + t4.z + t4.w;
            }
            #pragma unroll
            for (int off = 32; off; off >>= 1) s += __shfl_xor(s, off, 64);
            float bsum = bi[j] + bh[j];
            float q0 = Wq[0 * DIM + j], q1 = Wq[1 * DIM + j];
            float q2 = Wq[2 * DIM + j], q3 = Wq[3 * DIM + j];
            sv0 += q0 * s;    sv1 += q1 * s;    sv2 += q2 * s;    sv3 += q3 * s;
            sc0 += q0 * bsum; sc1 += q1 * bsum; sc2 += q2 * bsum; sc3 += q3 * bsum;
        }
        __shared__ float ls[4][8];
        if (lane == 0) {
            ls[wave][0] = sv0; ls[wave][1] = sv1; ls[wave][2] = sv2; ls[wave][3] = sv3;
            ls[wave][4] = sc0; ls[wave][5] = sc1; ls[wave][6] = sc2; ls[wave][7] = sc3;
        }
        __syncthreads();
        if (tid < 8) {
            float s = ls[0][tid] + ls[1][tid] + ls[2][tid] + ls[3][tid];
            if (tid < 4) vpart[bb_ * 4 + tid]       = s;
            else         cpart[bb_ * 4 + (tid - 4)] = s;
        }
    }
    grid.sync();

    // ---------- Phase A2: reduce partials ----------
    if (blk < 16) {
        int f = blk * 256 + tid;                       // 0..4095
        float s = 0.f;
        #pragma unroll 8
        for (int jc = 0; jc < 64; jc++) s += Mpart[(size_t)jc * 4096 + f];
        M[f] = s;
    } else if (blk == 16 && tid < 8) {
        const float* src = (tid < 4) ? vpart : cpart;
        int w = tid & 3;
        float s = 0.f;
        #pragma unroll 8
        for (int jc = 0; jc < 64; jc++) s += src[jc * 4 + w];
        if (tid < 4) v[w] = s; else cb[w] = s;
    }
    grid.sync();

    // ---------- Phase B: qx = x @ M.T, wave per row, 2-deep pipeline ----------
    {
        float4 m[4][4];
        #pragma unroll
        for (int w = 0; w < 4; w++)
            #pragma unroll
            for (int k = 0; k < 4; k++)
                m[w][k] = *(const float4*)(M + w * DIM + k * 256 + lane * 4);

        int NW = NB * 4;                               // total waves
        int r  = blk * 4 + wave;
        float4 cur[4];
        if (r < NROWS) {
            const float4* row = (const float4*)(x + (size_t)r * DIM);
            #pragma unroll
            for (int k = 0; k < 4; k++) cur[k] = row[k * 64 + lane];
        }
        while (r < NROWS) {
            int rn = r + NW;
            float4 nxt[4];
            if (rn < NROWS) {
                const float4* nrow = (const float4*)(x + (size_t)rn * DIM);
                #pragma unroll
                for (int k = 0; k < 4; k++) nxt[k] = nrow[k * 64 + lane];
            }
            float a0 = 0.f, a1 = 0.f, a2 = 0.f, a3 = 0.f;
            #pragma unroll
            for (int k = 0; k < 4; k++) {
                float4 xv = cur[k];
                a0 += xv.x * m[0][k].x + xv.y * m[0][k].y + xv.z * m[0][k].z + xv.w * m[0][k].w;
                a1 += xv.x * m[1][k].x + xv.y * m[1][k].y + xv.z * m[1][k].z + xv.w * m[1][k].w;
                a2 += xv.x * m[2][k].x + xv.y * m[2][k].y + xv.z * m[2][k].z + xv.w * m[2][k].w;
                a3 += xv.x * m[3][k].x + xv.y * m[3][k].y + xv.z * m[3][k].z + xv.w * m[3][k].w;
            }
            #pragma unroll
            for (int off = 32; off; off >>= 1) {
                a0 += __shfl_xor(a0, off, 64);
                a1 += __shfl_xor(a1, off, 64);
                a2 += __shfl_xor(a2, off, 64);
                a3 += __shfl_xor(a3, off, 64);
            }
            if (lane == 0) qx4[r] = make_float4(a0, a1, a2, a3);
            #pragma unroll
            for (int k = 0; k < 4; k++) cur[k] = nxt[k];
            r = rn;
        }
    }
    grid.sync();

    // ---------- Phase C: recurrence (block 0, 2 waves, unroll-8 prefetch) ----------
    if (blk == 0 && tid < BATCH) {
        int b = tid;
        float v0 = v[0], v1 = v[1], v2 = v[2], v3 = v[3];
        float b0 = cb[0] + bq[0] + theta[0];
        float b1 = cb[1] + bq[1] + theta[1];
        float b2 = cb[2] + bq[2] + theta[2];
        float b3 = cb[3] + bq[3] + theta[3];

        float h = 0.f, c = 0.f;
        float4 q0 = qx4[0 * BATCH + b], q1 = qx4[1 * BATCH + b];
        float4 q2 = qx4[2 * BATCH + b], q3 = qx4[3 * BATCH + b];
        float4 q4 = qx4[4 * BATCH + b], q5 = qx4[5 * BATCH + b];
        float4 q6 = qx4[6 * BATCH + b], q7 = qx4[7 * BATCH + b];

        for (int t = 0; t < T_STEPS; t += 8) {
            float4 n0, n1, n2, n3, n4, n5, n6, n7;
            if (t + 8 < T_STEPS) {
                n0 = qx4[(t + 8)  * BATCH + b];  n1 = qx4[(t + 9)  * BATCH + b];
                n2 = qx4[(t + 10) * BATCH + b];  n3 = qx4[(t + 11) * BATCH + b];
                n4 = qx4[(t + 12) * BATCH + b];  n5 = qx4[(t + 13) * BATCH + b];
                n6 = qx4[(t + 14) * BATCH + b];  n7 = qx4[(t + 15) * BATCH + b];
            }
            rec_step(q0, b0, b1, b2, b3, v0, v1, v2, v3, h, c); hseq[(t + 0) * BATCH + b] = h;
            rec_step(q1, b0, b1, b2, b3, v0, v1, v2, v3, h, c); hseq[(t + 1) * BATCH + b] = h;
            rec_step(q2, b0, b1, b2, b3, v0, v1, v2, v3, h, c); hseq[(t + 2) * BATCH + b] = h;
            rec_step(q3, b0, b1, b2, b3, v0, v1, v2, v3, h, c); hseq[(t + 3) * BATCH + b] = h;
            rec_step(q4, b0, b1, b2, b3, v0, v1, v2, v3, h, c); hseq[(t + 4) * BATCH + b] = h;
            rec_step(q5, b0, b1, b2, b3, v0, v1, v2, v3, h, c); hseq[(t + 5) * BATCH + b] = h;
            rec_step(q6, b0, b1, b2, b3, v0, v1, v2, v3, h, c); hseq[(t + 6) * BATCH + b] = h;
            rec_step(q7, b0, b1, b2, b3, v0, v1, v2, v3, h, c); hseq[(t + 7) * BATCH + b] = h;
            q0 = n0; q1 = n1; q2 = n2; q3 = n3; q4 = n4; q5 = n5; q6 = n6; q7 = n7;
        }
        cfin[b] = c;
    }
    grid.sync();

    // ---------- Phase D: broadcast write ----------
    for (int r = blk; r < TOTROWS; r += NB) {
        float val;
        if      (r < NROWS)         val = hseq[r];
        else if (r < NROWS + BATCH) val = hseq[(T_STEPS - 1) * BATCH + (r - NROWS)];
        else                        val = cfin[r - NROWS - BATCH];
        vfloat4 vv = {val, val, val, val};
        vfloat4* orow = (vfloat4*)(out + (size_t)r * DIM);
        __builtin_nontemporal_store(vv, &orow[tid]);
    }
}

extern "C" void kernel_launch(void* const* d_in, const int* in_sizes, int n_in,
                              void* d_out, int out_size, void* d_ws, size_t ws_size,
                              hipStream_t stream) {
    const float* inputs = (const float*)d_in[0];
    const float* Wi     = (const float*)d_in[1];
    const float* bi     = (const float*)d_in[2];
    const float* Wh     = (const float*)d_in[3];
    const float* bh     = (const float*)d_in[4];
    const float* Wq     = (const float*)d_in[5];
    const float* bq     = (const float*)d_in[6];
    const float* theta  = (const float*)d_in[7];
    float* out = (float*)d_out;
    float* ws  = (float*)d_ws;

    float*  M     = ws + WS_M;
    float*  v     = ws + WS_V;
    float*  cb    = ws + WS_CB;
    float4* qx4   = (float4*)(ws + WS_QX);
    float*  hseq  = ws + WS_HSEQ;
    float*  cfin  = ws + WS_CFIN;
    float*  Mpart = ws + WS_MPART;
    float*  vpart = ws + WS_VPART;
    float*  cpart = ws + WS_CPART;

    // pick largest co-residable grid (4 blocks/CU expected at VGPR=60)
    int perCU = 1;
    if (hipOccupancyMaxActiveBlocksPerMultiprocessor(&perCU, k_all, 256, 0)
            != hipSuccess || perCU < 1)
        perCU = 1;
    int nblk = 256 * perCU;
    if (nblk > 1024) nblk = 1024;   // 4096 waves is plenty; phases scale via gridDim

    void* args[] = { &inputs, &Wi, &Wh, &bi, &bh, &Wq, &bq, &theta,
                     &out, &M, &v, &cb, &qx4, &hseq, &cfin,
                     &Mpart, &vpart, &cpart };
    (void)hipLaunchCooperativeKernel((void*)k_all, dim3(nblk), dim3(256),
                                     args, 0, stream);
}

// Round 9
// 317.940 us; speedup vs baseline: 1.6700x; 1.6700x over previous
//
#include <hip/hip_runtime.h>

#define T_STEPS 256
#define BATCH   128
#define DIM     1024
#define NROWS   (T_STEPS * BATCH)        // 32768
#define TOTROWS (NROWS + 2 * BATCH)      // 33024

typedef float vfloat4 __attribute__((ext_vector_type(4)));

// ws float-offset layout
#define WS_M     0                        // float[4096]
#define WS_V     4096                     // float[4]
#define WS_CB    4128                     // float[4]
#define WS_ZERO_BYTES ((WS_CB + 4) * 4)   // memset covers M + v + cb
#define WS_QX    8192                     // float4[32768], layout [b][t]
#define WS_HSEQ  (WS_QX + 4 * NROWS)      // float[32768],  layout [b][t]
#define WS_CFIN  (WS_HSEQ + NROWS)        // float[128]

// ---------- prep: M = Wq@Wi and v/cb via fp32 HW atomics (ws pre-zeroed) ----------
__global__ __launch_bounds__(256) void k_prep(const float* __restrict__ Wi,
                                              const float* __restrict__ Wh,
                                              const float* __restrict__ bi,
                                              const float* __restrict__ bh,
                                              const float* __restrict__ Wq,
                                              float* __restrict__ M,
                                              float* __restrict__ v,
                                              float* __restrict__ cb) {
    int blk  = blockIdx.x;
    int tid  = threadIdx.x;
    int wave = tid >> 6;
    int lane = tid & 63;

    if (blk < 64) {
        int j0 = blk * 16;
        #pragma unroll
        for (int db = 0; db < 4; db++) {
            int d = db * 256 + tid;
            float a0 = 0.f, a1 = 0.f, a2 = 0.f, a3 = 0.f;
            #pragma unroll 4
            for (int jj = 0; jj < 16; jj++) {
                int j = j0 + jj;
                float wv = Wi[(size_t)j * DIM + d];   // coalesced 1KB/instr
                a0 += Wq[0 * DIM + j] * wv;           // uniform -> scalar loads
                a1 += Wq[1 * DIM + j] * wv;
                a2 += Wq[2 * DIM + j] * wv;
                a3 += Wq[3 * DIM + j] * wv;
            }
            unsafeAtomicAdd(&M[0 * DIM + d], a0);
            unsafeAtomicAdd(&M[1 * DIM + d], a1);
            unsafeAtomicAdd(&M[2 * DIM + d], a2);
            unsafeAtomicAdd(&M[3 * DIM + d], a3);
        }
    } else {
        int j0 = (blk - 64) * 16 + wave * 4;
        float sv0 = 0.f, sv1 = 0.f, sv2 = 0.f, sv3 = 0.f;
        float sc0 = 0.f, sc1 = 0.f, sc2 = 0.f, sc3 = 0.f;
        #pragma unroll
        for (int jj = 0; jj < 4; jj++) {
            int j = j0 + jj;
            const float4* row = (const float4*)(Wh + (size_t)j * DIM);
            float s = 0.f;
            #pragma unroll
            for (int k = 0; k < 4; k++) {
                float4 t4 = row[k * 64 + lane];
                s += t4.x + t4.y + t4.z + t4.w;
            }
            #pragma unroll
            for (int off = 32; off; off >>= 1) s += __shfl_xor(s, off, 64);
            float bsum = bi[j] + bh[j];
            float q0 = Wq[0 * DIM + j], q1 = Wq[1 * DIM + j];
            float q2 = Wq[2 * DIM + j], q3 = Wq[3 * DIM + j];
            sv0 += q0 * s;    sv1 += q1 * s;    sv2 += q2 * s;    sv3 += q3 * s;
            sc0 += q0 * bsum; sc1 += q1 * bsum; sc2 += q2 * bsum; sc3 += q3 * bsum;
        }
        if (lane == 0) {
            unsafeAtomicAdd(&v[0], sv0);  unsafeAtomicAdd(&v[1], sv1);
            unsafeAtomicAdd(&v[2], sv2);  unsafeAtomicAdd(&v[3], sv3);
            unsafeAtomicAdd(&cb[0], sc0); unsafeAtomicAdd(&cb[1], sc1);
            unsafeAtomicAdd(&cb[2], sc2); unsafeAtomicAdd(&cb[3], sc3);
        }
    }
}

// ---------- qx[b][t] = x[t*128+b] @ M.T ; wave per row ----------
__global__ __launch_bounds__(256) void k_qx(const float* __restrict__ x,
                                            const float* __restrict__ M,
                                            float4* __restrict__ qxT) {
    int gtid   = blockIdx.x * blockDim.x + threadIdx.x;
    int wave   = gtid >> 6;
    int lane   = threadIdx.x & 63;
    int nwaves = (gridDim.x * blockDim.x) >> 6;

    float4 m[4][4];                                    // M fragment in regs
    #pragma unroll
    for (int w = 0; w < 4; w++)
        #pragma unroll
        for (int k = 0; k < 4; k++)
            m[w][k] = *(const float4*)(M + w * DIM + k * 256 + lane * 4);

    for (int r = wave; r < NROWS; r += nwaves) {
        const float4* row = (const float4*)(x + (size_t)r * DIM);
        float a0 = 0.f, a1 = 0.f, a2 = 0.f, a3 = 0.f;
        #pragma unroll
        for (int k = 0; k < 4; k++) {
            float4 xv = row[k * 64 + lane];            // contiguous 1 KB/instr
            a0 += xv.x * m[0][k].x + xv.y * m[0][k].y + xv.z * m[0][k].z + xv.w * m[0][k].w;
            a1 += xv.x * m[1][k].x + xv.y * m[1][k].y + xv.z * m[1][k].z + xv.w * m[1][k].w;
            a2 += xv.x * m[2][k].x + xv.y * m[2][k].y + xv.z * m[2][k].z + xv.w * m[2][k].w;
            a3 += xv.x * m[3][k].x + xv.y * m[3][k].y + xv.z * m[3][k].z + xv.w * m[3][k].w;
        }
        #pragma unroll
        for (int off = 32; off; off >>= 1) {
            a0 += __shfl_xor(a0, off, 64);
            a1 += __shfl_xor(a1, off, 64);
            a2 += __shfl_xor(a2, off, 64);
            a3 += __shfl_xor(a3, off, 64);
        }
        if (lane == 0) {
            int t = r >> 7, b = r & 127;               // transpose: [b][t]
            qxT[(size_t)b * T_STEPS + t] = make_float4(a0, a1, a2, a3);
        }
    }
}

// ---------- recurrence: 2 waves, lane-contiguous loads, batched float4 stores ----------
__device__ __forceinline__ float fast_tanh(float x) {
    float e = __expf(2.f * x);
    return (e - 1.f) * __builtin_amdgcn_rcpf(e + 1.f);
}

__device__ __forceinline__ void rec_step(float4 q,
                                         float b0, float b1, float b2, float b3,
                                         float v0, float v1, float v2, float v3,
                                         float& h, float& c) {
    float z0 = __cosf(q.x + b0 + h * v0);
    float z1 = __cosf(q.y + b1 + h * v1);
    float z2 = __cosf(q.z + b2 + h * v2);
    float z3 = __cosf(q.w + b3 + h * v3);
    float e1 = z0 * z1;
    float e2 = e1 * z2;
    float e3 = e2 * z3;
    float e0 = z1 * z2 * z3;
    float x0 = __expf(e0), x1 = __expf(e1), x2 = __expf(e2), x3 = __expf(e3);
    float inv = __builtin_amdgcn_rcpf(x0 + x1 + x2 + x3);
    float f  = x0 * inv;
    float i_ = x1 * inv;
    float g  = x2 * inv;
    float o  = x3 * inv;
    c = f * c + i_ * fast_tanh(g);
    h = o * fast_tanh(c);
}

__global__ __launch_bounds__(128) void k_rec(const float* __restrict__ bq,
                                             const float* __restrict__ theta,
                                             const float* __restrict__ v,
                                             const float* __restrict__ cbp,
                                             const float4* __restrict__ qxT,
                                             float* __restrict__ hT,
                                             float* __restrict__ cfin) {
    int b = threadIdx.x;                      // one chain per lane

    float v0 = v[0], v1 = v[1], v2 = v[2], v3 = v[3];
    float b0 = cbp[0] + bq[0] + theta[0];
    float b1 = cbp[1] + bq[1] + theta[1];
    float b2 = cbp[2] + bq[2] + theta[2];
    float b3 = cbp[3] + bq[3] + theta[3];

    const float4* qrow = qxT + (size_t)b * T_STEPS;   // lane-contiguous 4 KB
    float4*       hrow = (float4*)(hT + (size_t)b * T_STEPS);

    float h = 0.f, c = 0.f;
    float4 q0 = qrow[0], q1 = qrow[1], q2 = qrow[2], q3 = qrow[3];
    float4 q4 = qrow[4], q5 = qrow[5], q6 = qrow[6], q7 = qrow[7];

    for (int t = 0; t < T_STEPS; t += 8) {
        float4 n0, n1, n2, n3, n4, n5, n6, n7;
        if (t + 8 < T_STEPS) {                // prefetch next 8 (contiguous 128 B)
            n0 = qrow[t + 8];  n1 = qrow[t + 9];  n2 = qrow[t + 10]; n3 = qrow[t + 11];
            n4 = qrow[t + 12]; n5 = qrow[t + 13]; n6 = qrow[t + 14]; n7 = qrow[t + 15];
        }
        float h0, h1, h2, h3, h4, h5, h6, h7;
        rec_step(q0, b0, b1, b2, b3, v0, v1, v2, v3, h, c); h0 = h;
        rec_step(q1, b0, b1, b2, b3, v0, v1, v2, v3, h, c); h1 = h;
        rec_step(q2, b0, b1, b2, b3, v0, v1, v2, v3, h, c); h2 = h;
        rec_step(q3, b0, b1, b2, b3, v0, v1, v2, v3, h, c); h3 = h;
        rec_step(q4, b0, b1, b2, b3, v0, v1, v2, v3, h, c); h4 = h;
        rec_step(q5, b0, b1, b2, b3, v0, v1, v2, v3, h, c); h5 = h;
        rec_step(q6, b0, b1, b2, b3, v0, v1, v2, v3, h, c); h6 = h;
        rec_step(q7, b0, b1, b2, b3, v0, v1, v2, v3, h, c); h7 = h;
        hrow[(t >> 2) + 0] = make_float4(h0, h1, h2, h3);   // 2 stores / 8 steps
        hrow[(t >> 2) + 1] = make_float4(h4, h5, h6, h7);
        q0 = n0; q1 = n1; q2 = n2; q3 = n3; q4 = n4; q5 = n5; q6 = n6; q7 = n7;
    }
    cfin[b] = c;
}

// ---------- broadcast write: 4 rows per block, nontemporal ----------
__global__ __launch_bounds__(256) void k_write(const float* __restrict__ hT,
                                               const float* __restrict__ cfin,
                                               float* __restrict__ out) {
    int tid  = threadIdx.x;
    int r    = blockIdx.x * 4 + (tid >> 6);
    int lane = tid & 63;

    float val;
    if      (r < NROWS)          val = hT[(size_t)(r & 127) * T_STEPS + (r >> 7)];
    else if (r < NROWS + BATCH)  val = hT[(size_t)(r - NROWS) * T_STEPS + (T_STEPS - 1)];
    else                         val = cfin[r - NROWS - BATCH];

    vfloat4 vv = {val, val, val, val};
    vfloat4* orow = (vfloat4*)(out + (size_t)r * DIM);
    __builtin_nontemporal_store(vv, &orow[0 * 64 + lane]);
    __builtin_nontemporal_store(vv, &orow[1 * 64 + lane]);
    __builtin_nontemporal_store(vv, &orow[2 * 64 + lane]);
    __builtin_nontemporal_store(vv, &orow[3 * 64 + lane]);
}

extern "C" void kernel_launch(void* const* d_in, const int* in_sizes, int n_in,
                              void* d_out, int out_size, void* d_ws, size_t ws_size,
                              hipStream_t stream) {
    const float* inputs = (const float*)d_in[0];
    const float* Wi     = (const float*)d_in[1];
    const float* bi     = (const float*)d_in[2];
    const float* Wh     = (const float*)d_in[3];
    const float* bh     = (const float*)d_in[4];
    const float* Wq     = (const float*)d_in[5];
    const float* bq     = (const float*)d_in[6];
    const float* theta  = (const float*)d_in[7];
    float* out = (float*)d_out;
    float* ws  = (float*)d_ws;

    float*  M    = ws + WS_M;
    float*  v    = ws + WS_V;
    float*  cb   = ws + WS_CB;
    float4* qxT  = (float4*)(ws + WS_QX);
    float*  hT   = ws + WS_HSEQ;
    float*  cfin = ws + WS_CFIN;

    (void)hipMemsetAsync(ws, 0, WS_ZERO_BYTES, stream);    // zero M + v + cb
    k_prep <<<128,  256, 0, stream>>>(Wi, Wh, bi, bh, Wq, M, v, cb);
    k_qx   <<<1024, 256, 0, stream>>>(inputs, M, qxT);
    k_rec  <<<1,    128, 0, stream>>>(bq, theta, v, cb, qxT, hT, cfin);
    k_write<<<TOTROWS / 4, 256, 0, stream>>>(hT, cfin, out);
}